// Round 12
// baseline (223.543 us; speedup 1.0000x reference)
//
#include <hip/hip_runtime.h>
#include <hip/hip_bf16.h>
#include <hip/hip_fp16.h>
#include <stdint.h>

#define D_MODEL 512
#define NH 8
#define DH 64
#define BB 2
#define SS 4096
#define MTOT (BB*SS)   // 8192

typedef __attribute__((ext_vector_type(8))) short bf16x8;
typedef __attribute__((ext_vector_type(4))) float f32x4;
typedef __fp16 fp16x2 __attribute__((ext_vector_type(2)));

#define MFMA32(a,b,c) __builtin_amdgcn_mfma_f32_16x16x32_bf16(a,b,c,0,0,0)

#if __has_builtin(__builtin_amdgcn_exp2f)
  #define EXP2F(x) __builtin_amdgcn_exp2f(x)
#else
  #define EXP2F(x) __expf((x) * 0.6931471805599453f)
#endif

// p = exp(s/8 - 8) = exp2(s*0.125*log2e - 8*log2e); 0.125*log2e folded into Q proj,
// -8*log2e folded into the QK MFMA accumulator init.
#define QSCALE 0.18033688011112042f   // 0.125 * log2(e)
#define EXPOFF 11.541560327679939f    // 8 * log2(e)

// round-half-up bf16: max error 0.5 ulp (same as RNE; only tie direction differs)
__device__ __forceinline__ unsigned f2b(float f) {
  return (__float_as_uint(f) + 0x8000u) >> 16;
}
__device__ __forceinline__ float h2f(unsigned short h) {
  return __half2float(__ushort_as_half(h));
}
// packed f32x2 -> f16x2 (RTZ), single VALU op, lo=src0
__device__ __forceinline__ unsigned packh2(float lo, float hi) {
  fp16x2 h = __builtin_amdgcn_cvt_pkrtz(lo, hi);
  return __builtin_bit_cast(unsigned, h);
}
__device__ __forceinline__ unsigned packpair(float lo, float hi) {
  return __builtin_amdgcn_perm(__float_as_uint(hi) + 0x8000u,
                               __float_as_uint(lo) + 0x8000u, 0x07060302u);
}
// packed f32x2 -> bf16x2 (RNE), single VALU op, lo=src0 (T12 primitive; no builtin)
__device__ __forceinline__ unsigned cvtpk_bf16(float lo, float hi) {
  unsigned r;
  asm("v_cvt_pk_bf16_f32 %0, %1, %2" : "=v"(r) : "v"(lo), "v"(hi));
  return r;
}
// async global->LDS DMA, 16B/lane: LDS dest = wave-uniform base + lane*16,
// global src is per-lane. Drained by the s_waitcnt vmcnt(0) that __syncthreads emits.
__device__ __forceinline__ void gload_lds16(const unsigned short* g, unsigned short* l) {
  __builtin_amdgcn_global_load_lds(
      (const __attribute__((address_space(1))) unsigned int*)g,
      (__attribute__((address_space(3))) unsigned int*)l, 16, 0, 0);
}

// ---------------- prep: cast fp32 -> bf16 (q,k,v, 4 weights) ----------------
// Tight 1D grid: blocks-per-slice via cumulative offsets. 8 elems/thread
// (2x float4 -> uint4). Coverage exact: every slice is a multiple of 2048.
struct PrepArgs {
  const float* src[7];
  unsigned short* dst[7];
  int off[8];   // cumulative block offsets; slice sizes are multiples of 2048
};

__global__ __launch_bounds__(256) void prep_kernel(PrepArgs a) {
  const int bx = blockIdx.x;
  int tgt = 0;
#pragma unroll
  for (int s = 1; s < 7; s++) tgt += (bx >= a.off[s]);
  const int i = ((bx - a.off[tgt]) * 256 + threadIdx.x) * 8;
  const float4 f0 = *(const float4*)(a.src[tgt] + i);
  const float4 f1 = *(const float4*)(a.src[tgt] + i + 4);
  uint4 o;
  o.x = packpair(f0.x, f0.y);
  o.y = packpair(f0.z, f0.w);
  o.z = packpair(f1.x, f1.y);
  o.w = packpair(f1.z, f1.w);
  *(uint4*)(a.dst[tgt] + i) = o;
}

// ---------------- GEMM: C[m][n] = sum_k A[m][k]*W[n][k] + bias[n] ----------------
// 128x128 tile, BK=32. R25: 2-phase double-buffered staging (catalog T3 minimum
// recipe, m248): stage(k+1) -> compute(k) -> __syncthreads, so the HBM DMA for
// k+1 flies UNDER compute(k). The old loop drained vmcnt(0) BEFORE compute —
// 16 fully-exposed ~900cy DMA waits per block; at N=512 these gemms are
// latency-bound (m102 shape curve: 18 TF @N=512 on this structure), so overlap
// is the right lever. Race-safety (one barrier/step): compute(cur) reads data
// completed by the PREVIOUS barrier's vmcnt(0); stage targets buf[cur^1], last
// read at step k-1, protected by that barrier; WAW drained likewise. LDS 32 KB.
// Staging via global_load_lds width=16 into LINEAR [128][32] (dest = uniform
// base + lane*16; padding would corrupt — m104/m173). Epilogue = scalar stores:
// lane-CONTIGUOUS 16-lane groups -> 4 tx/instr (R20: coalescing is CROSS-LANE).
// R20: XCD-chunked block swizzle (T1), bijective over 256 x,y-blocks.
// mode 0: z==0: Q*QSCALE -> [((b*NH+h)*SS+s)*DH+dh]
//         z==1: K        -> same layout
//         z==2: V^T col-swizzled -> [((b*NH+h)*DH+dh)*SS+perm(s)]
// mode 1: A = attn's normalized bf16 Ao; fp32 outf[m*512+n]
struct GemmArgs {
  const unsigned short* A[3];
  const unsigned short* W[3];
  const float* bias[3];
  unsigned short* out[3];
  float* outf;
  int mode;
};

__global__ __launch_bounds__(256) void gemm_kernel(GemmArgs g) {
  const int z = blockIdx.z;
  const float* __restrict__ bias = g.bias[z];
  unsigned short* __restrict__ out = g.out[z];
  const bool vt = (g.mode == 0) && (z == 2);
  const float osc = (g.mode == 0 && z == 0) ? QSCALE : 1.0f;

  __shared__ __align__(128) unsigned short lA[2][128][32];
  __shared__ __align__(128) unsigned short lB[2][128][32];

  const int t = threadIdx.x;
  const int lane = t & 63;
  const int w = t >> 6;
  const int wr = w >> 1, wc = w & 1;
  const int lrow = lane & 15, quad = lane >> 4;

  // XCD-chunked swizzle: orig = y*4+x in 0..255; logical chunk of 32 per XCD
  const int ob = blockIdx.y * 4 + blockIdx.x;
  const int lid = (ob & 7) * 32 + (ob >> 3);
  const int m0 = (lid >> 2) * 128;
  const int n0 = (lid & 3) * 128;

  const int srow = lane >> 2;          // 0..15: row within a 16-row DMA chunk
  const int schunk = (lane & 3) * 8;   // element col 0,8,16,24 (16B chunks)

  const unsigned short* __restrict__ Ag = g.A[z];
  const unsigned short* __restrict__ Wg = g.W[z];

  f32x4 acc[4][4];
  for (int i = 0; i < 4; i++)
    for (int j = 0; j < 4; j++)
      for (int r = 0; r < 4; r++) acc[i][j][r] = 0.f;

  // prologue: stage k-step 0 into buffer 0
#pragma unroll
  for (int i = 0; i < 2; i++) {
    const int r0 = w * 32 + i * 16;
    gload_lds16(Ag + (size_t)(m0 + r0 + srow) * 512 + schunk, &lA[0][r0][0]);
    gload_lds16(Wg + (size_t)(n0 + r0 + srow) * 512 + schunk, &lB[0][r0][0]);
  }
  __syncthreads();   // vmcnt(0) drain: buffer 0 resident

#pragma unroll 2
  for (int ks = 0; ks < 16; ks++) {
    const int cur = ks & 1;
    // stage k-step ks+1 into the other buffer; DMA flies under compute below
    if (ks + 1 < 16) {
      const int kk = (ks + 1) * 32;
#pragma unroll
      for (int i = 0; i < 2; i++) {
        const int r0 = w * 32 + i * 16;
        gload_lds16(Ag + (size_t)(m0 + r0 + srow) * 512 + kk + schunk, &lA[cur ^ 1][r0][0]);
        gload_lds16(Wg + (size_t)(n0 + r0 + srow) * 512 + kk + schunk, &lB[cur ^ 1][r0][0]);
      }
    }
    // compute on buffer cur (staged last step, completed by last barrier)
    bf16x8 af[4], bfr[4];
#pragma unroll
    for (int mt = 0; mt < 4; mt++) af[mt] = *(const bf16x8*)&lA[cur][wr * 64 + mt * 16 + lrow][quad * 8];
#pragma unroll
    for (int nt = 0; nt < 4; nt++) bfr[nt] = *(const bf16x8*)&lB[cur][wc * 64 + nt * 16 + lrow][quad * 8];
#pragma unroll
    for (int mt = 0; mt < 4; mt++)
#pragma unroll
      for (int nt = 0; nt < 4; nt++)
        acc[mt][nt] = MFMA32(af[mt], bfr[nt], acc[mt][nt]);
    __syncthreads();   // drains own DMAs (vmcnt 0) + all waves done reading cur
  }

  float bv[4];
#pragma unroll
  for (int nt = 0; nt < 4; nt++) bv[nt] = bias[n0 + wc * 64 + nt * 16 + lrow];

#pragma unroll
  for (int mt = 0; mt < 4; mt++) {
#pragma unroll
    for (int nt = 0; nt < 4; nt++) {
      const int n = n0 + wc * 64 + nt * 16 + lrow;
      const int mB = m0 + wr * 64 + mt * 16 + quad * 4;   // r=0 row
      float val[4];
#pragma unroll
      for (int r = 0; r < 4; r++) val[r] = (acc[mt][nt][r] + bv[nt]) * osc;

      if (g.mode == 1) {
#pragma unroll
        for (int r = 0; r < 4; r++) g.outf[(size_t)(mB + r) * 512 + n] = val[r];
      } else if (vt) {
        // V^T within-32-group swizzle: s=4a+r -> c = (s&~31)+(a&4)+((a&3)<<3)+r
        const int bb = mB >> 12, s = mB & 4095;
        const int a = s >> 2;
        const int c0 = (s & ~31) + (a & 4) + ((a & 3) << 3);
        const int hh = n >> 6, dh = n & 63;
        ushort4 pk = make_ushort4((unsigned short)f2b(val[0]), (unsigned short)f2b(val[1]),
                                  (unsigned short)f2b(val[2]), (unsigned short)f2b(val[3]));
        *(ushort4*)(out + (((size_t)bb * NH + hh) * DH + dh) * SS + c0) = pk;
      } else {
        const int bb = mB >> 12;
        const int hh = n >> 6, dh = n & 63;
#pragma unroll
        for (int r = 0; r < 4; r++) {
          const int s = (mB + r) & 4095;
          out[((((size_t)bb * NH + hh) * SS + s) << 6) + dh] = (unsigned short)f2b(val[r]);
        }
      }
    }
  }
}

// ---------------- flash attention, S^T formulation, NO j-split ----------------
// R25: attn FROZEN at R10 (two restructures — KVBLK=128 (R8), QBLK=128 (R11) —
// failed opaquely despite verified-identical math; this exact kernel is the
// proven 83.7us config). grid (16, NH, BB) = 256 blocks, 512 thr (8 waves),
// 32 Q-rows/WAVE, 64 KV-tiles per block. l completes in-kernel; epilogue
// normalizes (rcp) and writes FINAL bf16 Ao. K AND V staged in LDS, canonical
// 2-barrier + register prefetch. P^T in registers; PV = single MFMA32 per
// (half,nt,ti). P packed via v_cvt_pk_bf16_f32. Scalar fp32 lsum adds
// (v_pk_add_f32 asm BANNED — R4). NO setprio (R16).
struct AttnArgs {
  const unsigned short* Qh;
  const unsigned short* Kh;
  const unsigned short* Vt;
  unsigned short* Ao;
};

__global__ __launch_bounds__(512, 4) void attn_kernel(AttnArgs a) {
  __shared__ __align__(16) unsigned short lK[64][72];
  __shared__ __align__(16) unsigned short lV[64][72];

  const int t = threadIdx.x;
  const int lane = t & 63;
  const int w = t >> 6;                       // 0..7
  const int lrow = lane & 15, quad = lane >> 4;
  const int h = blockIdx.y, b = blockIdx.z;
  const int qtile = blockIdx.x;               // 0..15
  const size_t kb = ((size_t)b * NH + h) * SS * DH;   // Q,K: [s][dh]
  const size_t vb = ((size_t)b * NH + h) * DH * SS;   // V^T: [dh][s'] swizzled
  const int qrow0 = qtile * 256 + w * 32;

  bf16x8 qf[2][2];
#pragma unroll
  for (int ti = 0; ti < 2; ti++) {
    const unsigned short* qp = a.Qh + kb + (size_t)(qrow0 + ti * 16 + lrow) * DH + quad * 8;
    qf[ti][0] = *(const bf16x8*)qp;
    qf[ti][1] = *(const bf16x8*)(qp + 32);
  }

  f32x4 o[2][4];
  float lsum[2] = {0.f, 0.f};
#pragma unroll
  for (int ti = 0; ti < 2; ti++)
    for (int nt = 0; nt < 4; nt++)
      for (int r = 0; r < 4; r++) o[ti][nt][r] = 0.f;

  const unsigned short* __restrict__ Kg = a.Kh + kb;
  const unsigned short* __restrict__ Vg = a.Vt + vb;

  // 512 threads stage one 64x64 bf16 tile each for K and V: one uint4 per thread
  const int rk = t >> 3;          // 0..63
  const int ck = (t & 7) * 8;     // 0..56

  uint4 kreg = *(const uint4*)(Kg + (size_t)rk * DH + ck);
  uint4 vreg = *(const uint4*)(Vg + (size_t)rk * SS + ck);

  const f32x4 sinit = {-EXPOFF, -EXPOFF, -EXPOFF, -EXPOFF};

  for (int jt = 0; jt < 64; jt++) {
    __syncthreads();   // all waves done READING lK/lV (previous iteration)
    *(uint4*)&lK[rk][ck] = kreg;
    *(uint4*)&lV[rk][ck] = vreg;
    {
      const int nb = (jt + 1 < 64 ? jt + 1 : jt) * 64;
      kreg = *(const uint4*)(Kg + (size_t)(nb + rk) * DH + ck);
      vreg = *(const uint4*)(Vg + (size_t)rk * SS + nb + ck);
    }
    __syncthreads();   // tile jt visible to all waves

#pragma unroll
    for (int half = 0; half < 2; half++) {
      uint2 pw[2][2];   // [u][ti]
#pragma unroll
      for (int u = 0; u < 2; u++) {
        const int ntj = half * 2 + u;
        bf16x8 k0 = *(const bf16x8*)&lK[ntj * 16 + lrow][quad * 8];
        bf16x8 k1 = *(const bf16x8*)&lK[ntj * 16 + lrow][32 + quad * 8];
#pragma unroll
        for (int ti = 0; ti < 2; ti++) {
          f32x4 s = MFMA32(k0, qf[ti][0], sinit);
          s = MFMA32(k1, qf[ti][1], s);
          const float e0 = EXP2F(s[0]);
          const float e1 = EXP2F(s[1]);
          const float e2 = EXP2F(s[2]);
          const float e3 = EXP2F(s[3]);
          lsum[ti] += (e0 + e1) + (e2 + e3);
          pw[u][ti].x = cvtpk_bf16(e0, e1);
          pw[u][ti].y = cvtpk_bf16(e2, e3);
        }
      }
      bf16x8 pcat[2];
#pragma unroll
      for (int ti = 0; ti < 2; ti++) {
        uint4 c;
        c.x = pw[0][ti].x; c.y = pw[0][ti].y;
        c.z = pw[1][ti].x; c.w = pw[1][ti].y;
        pcat[ti] = __builtin_bit_cast(bf16x8, c);
      }
#pragma unroll
      for (int nt = 0; nt < 4; nt++) {
        bf16x8 vv = *(const bf16x8*)&lV[nt * 16 + lrow][half * 32 + quad * 8];
#pragma unroll
        for (int ti = 0; ti < 2; ti++)
          o[ti][nt] = MFMA32(vv, pcat[ti], o[ti][nt]);
      }
    }
  }

  // epilogue: cross-quad reduce l (row si's p-mass is spread over the 4 quads),
  // normalize in-register, write FINAL bf16 O.
#pragma unroll
  for (int ti = 0; ti < 2; ti++) {
    float l = lsum[ti];
    l += __shfl_xor(l, 16);
    l += __shfl_xor(l, 32);
    const float inv = __builtin_amdgcn_rcpf(l);
    const int si = qrow0 + ti * 16 + lrow;
    unsigned short* dst = a.Ao + ((size_t)(b * SS + si)) * D_MODEL + h * DH;
#pragma unroll
    for (int nt = 0; nt < 4; nt++) {
      uint2 pk;
      pk.x = cvtpk_bf16(o[ti][nt][0] * inv, o[ti][nt][1] * inv);
      pk.y = cvtpk_bf16(o[ti][nt][2] * inv, o[ti][nt][3] * inv);
      *(uint2*)(dst + nt * 16 + quad * 4) = pk;
    }
  }
}

// ---------------- launch ----------------
extern "C" void kernel_launch(void* const* d_in, const int* in_sizes, int n_in,
                              void* d_out, int out_size, void* d_ws, size_t ws_size,
                              hipStream_t stream) {
  const float* q  = (const float*)d_in[0];
  const float* k  = (const float*)d_in[1];
  const float* v  = (const float*)d_in[2];
  const float* Wq = (const float*)d_in[3];
  const float* bq = (const float*)d_in[4];
  const float* Wk = (const float*)d_in[5];
  const float* bk = (const float*)d_in[6];
  const float* Wv = (const float*)d_in[7];
  const float* bv = (const float*)d_in[8];
  const float* Wo = (const float*)d_in[9];
  const float* bo = (const float*)d_in[10];

  const size_t NX = (size_t)MTOT * D_MODEL;     // 4,194,304
  const size_t NW = (size_t)D_MODEL * D_MODEL;  // 262,144

  char* p = (char*)d_ws;
  unsigned short* qb  = (unsigned short*)p; p += NX * 2;
  unsigned short* kbf = (unsigned short*)p; p += NX * 2;
  unsigned short* vbf = (unsigned short*)p; p += NX * 2;
  unsigned short* Wqb = (unsigned short*)p; p += NW * 2;
  unsigned short* Wkb = (unsigned short*)p; p += NW * 2;
  unsigned short* Wvb = (unsigned short*)p; p += NW * 2;
  unsigned short* Wob = (unsigned short*)p; p += NW * 2;
  unsigned short* Qh  = (unsigned short*)p; p += NX * 2;
  unsigned short* Kh  = (unsigned short*)p; p += NX * 2;
  unsigned short* Vtg = (unsigned short*)p; p += NX * 2;
  unsigned short* Ao  = (unsigned short*)p; p += NX * 2;

  PrepArgs pr;
  pr.src[0] = q;  pr.dst[0] = qb;
  pr.src[1] = k;  pr.dst[1] = kbf;
  pr.src[2] = v;  pr.dst[2] = vbf;
  pr.src[3] = Wq; pr.dst[3] = Wqb;
  pr.src[4] = Wk; pr.dst[4] = Wkb;
  pr.src[5] = Wv; pr.dst[5] = Wvb;
  pr.src[6] = Wo; pr.dst[6] = Wob;
  {
    const int nb[7] = {(int)(NX / 2048), (int)(NX / 2048), (int)(NX / 2048),
                       (int)(NW / 2048), (int)(NW / 2048), (int)(NW / 2048),
                       (int)(NW / 2048)};
    int acc = 0;
    for (int i = 0; i < 7; i++) { pr.off[i] = acc; acc += nb[i]; }
    pr.off[7] = acc;
    prep_kernel<<<dim3(acc, 1, 1), 256, 0, stream>>>(pr);
  }

  GemmArgs pa;
  pa.A[0] = qb; pa.A[1] = kbf; pa.A[2] = vbf;
  pa.W[0] = Wqb; pa.W[1] = Wkb; pa.W[2] = Wvb;
  pa.bias[0] = bq; pa.bias[1] = bk; pa.bias[2] = bv;
  pa.out[0] = Qh; pa.out[1] = Kh; pa.out[2] = Vtg;
  pa.outf = nullptr;
  pa.mode = 0;
  gemm_kernel<<<dim3(4, 64, 3), 256, 0, stream>>>(pa);

  AttnArgs aa;
  aa.Qh = Qh; aa.Kh = Kh; aa.Vt = Vtg; aa.Ao = Ao;
  attn_kernel<<<dim3(16, NH, BB), 512, 0, stream>>>(aa);

  GemmArgs oa;
  oa.A[0] = Ao; oa.A[1] = Ao; oa.A[2] = Ao;
  oa.W[0] = Wob; oa.W[1] = Wob; oa.W[2] = Wob;
  oa.bias[0] = bo; oa.bias[1] = bo; oa.bias[2] = bo;
  oa.out[0] = nullptr; oa.out[1] = nullptr; oa.out[2] = nullptr;
  oa.outf = (float*)d_out;
  oa.mode = 1;
  gemm_kernel<<<dim3(4, 64, 1), 256, 0, stream>>>(oa);
}

// Round 13
// 213.354 us; speedup vs baseline: 1.0478x; 1.0478x over previous
//
#include <hip/hip_runtime.h>
#include <hip/hip_bf16.h>
#include <hip/hip_fp16.h>
#include <stdint.h>

#define D_MODEL 512
#define NH 8
#define DH 64
#define BB 2
#define SS 4096
#define MTOT (BB*SS)   // 8192

typedef __attribute__((ext_vector_type(8))) short bf16x8;
typedef __attribute__((ext_vector_type(4))) float f32x4;
typedef __fp16 fp16x2 __attribute__((ext_vector_type(2)));

#define MFMA32(a,b,c) __builtin_amdgcn_mfma_f32_16x16x32_bf16(a,b,c,0,0,0)

#if __has_builtin(__builtin_amdgcn_exp2f)
  #define EXP2F(x) __builtin_amdgcn_exp2f(x)
#else
  #define EXP2F(x) __expf((x) * 0.6931471805599453f)
#endif

// p = exp(s/8 - 8) = exp2(s*0.125*log2e - 8*log2e); 0.125*log2e folded into Q proj,
// -8*log2e folded into the QK MFMA accumulator init.
#define QSCALE 0.18033688011112042f   // 0.125 * log2(e)
#define EXPOFF 11.541560327679939f    // 8 * log2(e)

// round-half-up bf16: max error 0.5 ulp (same as RNE; only tie direction differs)
__device__ __forceinline__ unsigned f2b(float f) {
  return (__float_as_uint(f) + 0x8000u) >> 16;
}
__device__ __forceinline__ float h2f(unsigned short h) {
  return __half2float(__ushort_as_half(h));
}
// packed f32x2 -> f16x2 (RTZ), single VALU op, lo=src0
__device__ __forceinline__ unsigned packh2(float lo, float hi) {
  fp16x2 h = __builtin_amdgcn_cvt_pkrtz(lo, hi);
  return __builtin_bit_cast(unsigned, h);
}
__device__ __forceinline__ unsigned packpair(float lo, float hi) {
  return __builtin_amdgcn_perm(__float_as_uint(hi) + 0x8000u,
                               __float_as_uint(lo) + 0x8000u, 0x07060302u);
}
// packed f32x2 -> bf16x2 (RNE), single VALU op, lo=src0 (T12 primitive; no builtin)
__device__ __forceinline__ unsigned cvtpk_bf16(float lo, float hi) {
  unsigned r;
  asm("v_cvt_pk_bf16_f32 %0, %1, %2" : "=v"(r) : "v"(lo), "v"(hi));
  return r;
}
// async global->LDS DMA, 16B/lane: LDS dest = wave-uniform base + lane*16,
// global src is per-lane. Drained by the s_waitcnt vmcnt(0) that __syncthreads emits.
__device__ __forceinline__ void gload_lds16(const unsigned short* g, unsigned short* l) {
  __builtin_amdgcn_global_load_lds(
      (const __attribute__((address_space(1))) unsigned int*)g,
      (__attribute__((address_space(3))) unsigned int*)l, 16, 0, 0);
}

// ---------------- prep: cast fp32 -> bf16 (q,k,v, 4 weights) ----------------
// Tight 1D grid: blocks-per-slice via cumulative offsets. 8 elems/thread
// (2x float4 -> uint4). Coverage exact: every slice is a multiple of 2048.
struct PrepArgs {
  const float* src[7];
  unsigned short* dst[7];
  int off[8];   // cumulative block offsets; slice sizes are multiples of 2048
};

__global__ __launch_bounds__(256) void prep_kernel(PrepArgs a) {
  const int bx = blockIdx.x;
  int tgt = 0;
#pragma unroll
  for (int s = 1; s < 7; s++) tgt += (bx >= a.off[s]);
  const int i = ((bx - a.off[tgt]) * 256 + threadIdx.x) * 8;
  const float4 f0 = *(const float4*)(a.src[tgt] + i);
  const float4 f1 = *(const float4*)(a.src[tgt] + i + 4);
  uint4 o;
  o.x = packpair(f0.x, f0.y);
  o.y = packpair(f0.z, f0.w);
  o.z = packpair(f1.x, f1.y);
  o.w = packpair(f1.z, f1.w);
  *(uint4*)(a.dst[tgt] + i) = o;
}

// ---------------- GEMM: C[m][n] = sum_k A[m][k]*W[n][k] + bias[n] ----------------
// 128x128 tile, BK=32, SINGLE-buffer (R25's explicit dbuf REVERTED — regressed
// ~9us: __syncthreads' vmcnt(0) drains the just-issued prefetch DMAs at the same
// barrier, so overlap was zero and 2x LDS + loop overhead were pure cost; the
// catalog's m99/m100 documents exactly this. Breaking it needs raw-barrier
// counted-vmcnt — a multi-round race-screened project, not a drop-in).
// Staging via global_load_lds width=16 into LINEAR [128][32] (dest = uniform
// base + lane*16; padding/swizzle would corrupt — m104/m173). Epilogue = scalar
// stores: lane-CONTIGUOUS 16-lane groups -> 4 tx/instr (R20: coalescing is
// CROSS-LANE). R20: XCD-chunked block swizzle (T1), bijective over 256 blocks.
// mode 0: z==0: Q*QSCALE -> [((b*NH+h)*SS+s)*DH+dh]
//         z==1: K        -> same layout
//         z==2: V^T col-swizzled -> [((b*NH+h)*DH+dh)*SS+perm(s)]
// mode 1: A = attn's normalized bf16 Ao; fp32 outf[m*512+n]
struct GemmArgs {
  const unsigned short* A[3];
  const unsigned short* W[3];
  const float* bias[3];
  unsigned short* out[3];
  float* outf;
  int mode;
};

__global__ __launch_bounds__(256) void gemm_kernel(GemmArgs g) {
  const int z = blockIdx.z;
  const float* __restrict__ bias = g.bias[z];
  unsigned short* __restrict__ out = g.out[z];
  const bool vt = (g.mode == 0) && (z == 2);
  const float osc = (g.mode == 0 && z == 0) ? QSCALE : 1.0f;

  __shared__ __align__(128) unsigned short lA[128][32];
  __shared__ __align__(128) unsigned short lB[128][32];

  const int t = threadIdx.x;
  const int lane = t & 63;
  const int w = t >> 6;
  const int wr = w >> 1, wc = w & 1;
  const int lrow = lane & 15, quad = lane >> 4;

  // XCD-chunked swizzle: orig = y*4+x in 0..255; logical chunk of 32 per XCD
  const int ob = blockIdx.y * 4 + blockIdx.x;
  const int lid = (ob & 7) * 32 + (ob >> 3);
  const int m0 = (lid >> 2) * 128;
  const int n0 = (lid & 3) * 128;

  const int srow = lane >> 2;          // 0..15: row within a 16-row DMA chunk
  const int schunk = (lane & 3) * 8;   // element col 0,8,16,24 (16B chunks)

  const unsigned short* __restrict__ Ag = g.A[z];
  const unsigned short* __restrict__ Wg = g.W[z];

  f32x4 acc[4][4];
  for (int i = 0; i < 4; i++)
    for (int j = 0; j < 4; j++)
      for (int r = 0; r < 4; r++) acc[i][j][r] = 0.f;

  for (int kk = 0; kk < 512; kk += 32) {
    // each wave DMAs rows [w*32, w*32+32) of the A and B tiles (2x16 rows each)
#pragma unroll
    for (int i = 0; i < 2; i++) {
      const int r0 = w * 32 + i * 16;
      gload_lds16(Ag + (size_t)(m0 + r0 + srow) * 512 + kk + schunk, &lA[r0][0]);
      gload_lds16(Wg + (size_t)(n0 + r0 + srow) * 512 + kk + schunk, &lB[r0][0]);
    }
    __syncthreads();   // drains vmcnt(0): tile resident + all waves aligned
    bf16x8 af[4], bfr[4];
#pragma unroll
    for (int mt = 0; mt < 4; mt++) af[mt] = *(const bf16x8*)&lA[wr * 64 + mt * 16 + lrow][quad * 8];
#pragma unroll
    for (int nt = 0; nt < 4; nt++) bfr[nt] = *(const bf16x8*)&lB[wc * 64 + nt * 16 + lrow][quad * 8];
#pragma unroll
    for (int mt = 0; mt < 4; mt++)
#pragma unroll
      for (int nt = 0; nt < 4; nt++)
        acc[mt][nt] = MFMA32(af[mt], bfr[nt], acc[mt][nt]);
    __syncthreads();   // all waves done reading before next DMA overwrites
  }

  float bv[4];
#pragma unroll
  for (int nt = 0; nt < 4; nt++) bv[nt] = bias[n0 + wc * 64 + nt * 16 + lrow];

#pragma unroll
  for (int mt = 0; mt < 4; mt++) {
#pragma unroll
    for (int nt = 0; nt < 4; nt++) {
      const int n = n0 + wc * 64 + nt * 16 + lrow;
      const int mB = m0 + wr * 64 + mt * 16 + quad * 4;   // r=0 row
      float val[4];
#pragma unroll
      for (int r = 0; r < 4; r++) val[r] = (acc[mt][nt][r] + bv[nt]) * osc;

      if (g.mode == 1) {
#pragma unroll
        for (int r = 0; r < 4; r++) g.outf[(size_t)(mB + r) * 512 + n] = val[r];
      } else if (vt) {
        // V^T within-32-group swizzle: s=4a+r -> c = (s&~31)+(a&4)+((a&3)<<3)+r
        const int bb = mB >> 12, s = mB & 4095;
        const int a = s >> 2;
        const int c0 = (s & ~31) + (a & 4) + ((a & 3) << 3);
        const int hh = n >> 6, dh = n & 63;
        ushort4 pk = make_ushort4((unsigned short)f2b(val[0]), (unsigned short)f2b(val[1]),
                                  (unsigned short)f2b(val[2]), (unsigned short)f2b(val[3]));
        *(ushort4*)(out + (((size_t)bb * NH + hh) * DH + dh) * SS + c0) = pk;
      } else {
        const int bb = mB >> 12;
        const int hh = n >> 6, dh = n & 63;
#pragma unroll
        for (int r = 0; r < 4; r++) {
          const int s = (mB + r) & 4095;
          out[((((size_t)bb * NH + hh) * SS + s) << 6) + dh] = (unsigned short)f2b(val[r]);
        }
      }
    }
  }
}

// ---------------- flash attention, S^T formulation, NO j-split ----------------
// Structure FROZEN at R10 (two structural restructures failed opaquely); R26
// adds ONLY a T2 XOR chunk swizzle to the LDS addressing — legal here because
// attn staging is reg-staged uint4 (NOT global_load_lds), and bijective per row:
// 16B-chunk c of row r sits at LDS chunk c ^ (r&7); write and read use the SAME
// involution (rule #21). Why: [64][72]'s row stride ≡ 4 dwords (mod 32) put
// every 8-lane b128 phase on ~4 bank-starts -> measured 8.4M SQ_LDS_BANK_CONFLICT.
// After swizzle each phase reads 8 distinct chunks = all 32 banks. LDS [64][64]
// linear (18.4 -> 16 KB). Math order untouched.
// grid (16, NH, BB) = 256 blocks, 512 thr (8 waves), 32 Q-rows/WAVE, 64 KV
// tiles/block. l completes in-kernel; epilogue normalizes (rcp) and writes
// FINAL bf16 Ao. Canonical 2-barrier + register prefetch. P^T in registers;
// PV = single MFMA32 per (half,nt,ti). P packed via v_cvt_pk_bf16_f32. Scalar
// fp32 lsum adds (v_pk_add_f32 asm BANNED — R4). NO setprio (R16).
struct AttnArgs {
  const unsigned short* Qh;
  const unsigned short* Kh;
  const unsigned short* Vt;
  unsigned short* Ao;
};

__global__ __launch_bounds__(512, 4) void attn_kernel(AttnArgs a) {
  __shared__ __align__(16) unsigned short lK[64][64];
  __shared__ __align__(16) unsigned short lV[64][64];

  const int t = threadIdx.x;
  const int lane = t & 63;
  const int w = t >> 6;                       // 0..7
  const int lrow = lane & 15, quad = lane >> 4;
  const int h = blockIdx.y, b = blockIdx.z;
  const int qtile = blockIdx.x;               // 0..15
  const size_t kb = ((size_t)b * NH + h) * SS * DH;   // Q,K: [s][dh]
  const size_t vb = ((size_t)b * NH + h) * DH * SS;   // V^T: [dh][s'] swizzled
  const int qrow0 = qtile * 256 + w * 32;

  bf16x8 qf[2][2];
#pragma unroll
  for (int ti = 0; ti < 2; ti++) {
    const unsigned short* qp = a.Qh + kb + (size_t)(qrow0 + ti * 16 + lrow) * DH + quad * 8;
    qf[ti][0] = *(const bf16x8*)qp;
    qf[ti][1] = *(const bf16x8*)(qp + 32);
  }

  f32x4 o[2][4];
  float lsum[2] = {0.f, 0.f};
#pragma unroll
  for (int ti = 0; ti < 2; ti++)
    for (int nt = 0; nt < 4; nt++)
      for (int r = 0; r < 4; r++) o[ti][nt][r] = 0.f;

  const unsigned short* __restrict__ Kg = a.Kh + kb;
  const unsigned short* __restrict__ Vg = a.Vt + vb;

  // 512 threads stage one 64x64 bf16 tile each for K and V: one uint4 per
  // thread. LDS chunk-XOR swizzle: global chunk (t&7) of row rk lands at LDS
  // chunk (t&7)^(rk&7). Write phases (8 lanes = one row) cover all 8 chunks.
  const int rk = t >> 3;                       // 0..63
  const int ckg = (t & 7) * 8;                 // global col (ush), linear
  const int cks = (((t & 7) ^ (rk & 7))) * 8;  // swizzled LDS col (ush)

  uint4 kreg = *(const uint4*)(Kg + (size_t)rk * DH + ckg);
  uint4 vreg = *(const uint4*)(Vg + (size_t)rk * SS + ckg);

  const f32x4 sinit = {-EXPOFF, -EXPOFF, -EXPOFF, -EXPOFF};

  for (int jt = 0; jt < 64; jt++) {
    __syncthreads();   // all waves done READING lK/lV (previous iteration)
    *(uint4*)&lK[rk][cks] = kreg;
    *(uint4*)&lV[rk][cks] = vreg;
    {
      const int nb = (jt + 1 < 64 ? jt + 1 : jt) * 64;
      kreg = *(const uint4*)(Kg + (size_t)(nb + rk) * DH + ckg);
      vreg = *(const uint4*)(Vg + (size_t)rk * SS + nb + ckg);
    }
    __syncthreads();   // tile jt visible to all waves

    const int sw = lrow & 7;   // row&7 for all rows ntj*16+lrow (16 ≡ 0 mod 8)
#pragma unroll
    for (int half = 0; half < 2; half++) {
      uint2 pw[2][2];   // [u][ti]
#pragma unroll
      for (int u = 0; u < 2; u++) {
        const int ntj = half * 2 + u;
        bf16x8 k0 = *(const bf16x8*)&lK[ntj * 16 + lrow][(quad ^ sw) * 8];
        bf16x8 k1 = *(const bf16x8*)&lK[ntj * 16 + lrow][((4 | quad) ^ sw) * 8];
#pragma unroll
        for (int ti = 0; ti < 2; ti++) {
          f32x4 s = MFMA32(k0, qf[ti][0], sinit);
          s = MFMA32(k1, qf[ti][1], s);
          const float e0 = EXP2F(s[0]);
          const float e1 = EXP2F(s[1]);
          const float e2 = EXP2F(s[2]);
          const float e3 = EXP2F(s[3]);
          lsum[ti] += (e0 + e1) + (e2 + e3);
          pw[u][ti].x = cvtpk_bf16(e0, e1);
          pw[u][ti].y = cvtpk_bf16(e2, e3);
        }
      }
      bf16x8 pcat[2];
#pragma unroll
      for (int ti = 0; ti < 2; ti++) {
        uint4 c;
        c.x = pw[0][ti].x; c.y = pw[0][ti].y;
        c.z = pw[1][ti].x; c.w = pw[1][ti].y;
        pcat[ti] = __builtin_bit_cast(bf16x8, c);
      }
#pragma unroll
      for (int nt = 0; nt < 4; nt++) {
        bf16x8 vv = *(const bf16x8*)&lV[nt * 16 + lrow][((half * 4 + quad) ^ sw) * 8];
#pragma unroll
        for (int ti = 0; ti < 2; ti++)
          o[ti][nt] = MFMA32(vv, pcat[ti], o[ti][nt]);
      }
    }
  }

  // epilogue: cross-quad reduce l (row si's p-mass is spread over the 4 quads),
  // normalize in-register, write FINAL bf16 O.
#pragma unroll
  for (int ti = 0; ti < 2; ti++) {
    float l = lsum[ti];
    l += __shfl_xor(l, 16);
    l += __shfl_xor(l, 32);
    const float inv = __builtin_amdgcn_rcpf(l);
    const int si = qrow0 + ti * 16 + lrow;
    unsigned short* dst = a.Ao + ((size_t)(b * SS + si)) * D_MODEL + h * DH;
#pragma unroll
    for (int nt = 0; nt < 4; nt++) {
      uint2 pk;
      pk.x = cvtpk_bf16(o[ti][nt][0] * inv, o[ti][nt][1] * inv);
      pk.y = cvtpk_bf16(o[ti][nt][2] * inv, o[ti][nt][3] * inv);
      *(uint2*)(dst + nt * 16 + quad * 4) = pk;
    }
  }
}

// ---------------- launch ----------------
extern "C" void kernel_launch(void* const* d_in, const int* in_sizes, int n_in,
                              void* d_out, int out_size, void* d_ws, size_t ws_size,
                              hipStream_t stream) {
  const float* q  = (const float*)d_in[0];
  const float* k  = (const float*)d_in[1];
  const float* v  = (const float*)d_in[2];
  const float* Wq = (const float*)d_in[3];
  const float* bq = (const float*)d_in[4];
  const float* Wk = (const float*)d_in[5];
  const float* bk = (const float*)d_in[6];
  const float* Wv = (const float*)d_in[7];
  const float* bv = (const float*)d_in[8];
  const float* Wo = (const float*)d_in[9];
  const float* bo = (const float*)d_in[10];

  const size_t NX = (size_t)MTOT * D_MODEL;     // 4,194,304
  const size_t NW = (size_t)D_MODEL * D_MODEL;  // 262,144

  char* p = (char*)d_ws;
  unsigned short* qb  = (unsigned short*)p; p += NX * 2;
  unsigned short* kbf = (unsigned short*)p; p += NX * 2;
  unsigned short* vbf = (unsigned short*)p; p += NX * 2;
  unsigned short* Wqb = (unsigned short*)p; p += NW * 2;
  unsigned short* Wkb = (unsigned short*)p; p += NW * 2;
  unsigned short* Wvb = (unsigned short*)p; p += NW * 2;
  unsigned short* Wob = (unsigned short*)p; p += NW * 2;
  unsigned short* Qh  = (unsigned short*)p; p += NX * 2;
  unsigned short* Kh  = (unsigned short*)p; p += NX * 2;
  unsigned short* Vtg = (unsigned short*)p; p += NX * 2;
  unsigned short* Ao  = (unsigned short*)p; p += NX * 2;

  PrepArgs pr;
  pr.src[0] = q;  pr.dst[0] = qb;
  pr.src[1] = k;  pr.dst[1] = kbf;
  pr.src[2] = v;  pr.dst[2] = vbf;
  pr.src[3] = Wq; pr.dst[3] = Wqb;
  pr.src[4] = Wk; pr.dst[4] = Wkb;
  pr.src[5] = Wv; pr.dst[5] = Wvb;
  pr.src[6] = Wo; pr.dst[6] = Wob;
  {
    const int nb[7] = {(int)(NX / 2048), (int)(NX / 2048), (int)(NX / 2048),
                       (int)(NW / 2048), (int)(NW / 2048), (int)(NW / 2048),
                       (int)(NW / 2048)};
    int acc = 0;
    for (int i = 0; i < 7; i++) { pr.off[i] = acc; acc += nb[i]; }
    pr.off[7] = acc;
    prep_kernel<<<dim3(acc, 1, 1), 256, 0, stream>>>(pr);
  }

  GemmArgs pa;
  pa.A[0] = qb; pa.A[1] = kbf; pa.A[2] = vbf;
  pa.W[0] = Wqb; pa.W[1] = Wkb; pa.W[2] = Wvb;
  pa.bias[0] = bq; pa.bias[1] = bk; pa.bias[2] = bv;
  pa.out[0] = Qh; pa.out[1] = Kh; pa.out[2] = Vtg;
  pa.outf = nullptr;
  pa.mode = 0;
  gemm_kernel<<<dim3(4, 64, 3), 256, 0, stream>>>(pa);

  AttnArgs aa;
  aa.Qh = Qh; aa.Kh = Kh; aa.Vt = Vtg; aa.Ao = Ao;
  attn_kernel<<<dim3(16, NH, BB), 512, 0, stream>>>(aa);

  GemmArgs oa;
  oa.A[0] = Ao; oa.A[1] = Ao; oa.A[2] = Ao;
  oa.W[0] = Wob; oa.W[1] = Wob; oa.W[2] = Wob;
  oa.bias[0] = bo; oa.bias[1] = bo; oa.bias[2] = bo;
  oa.out[0] = nullptr; oa.out[1] = nullptr; oa.out[2] = nullptr;
  oa.outf = (float*)d_out;
  oa.mode = 1;
  gemm_kernel<<<dim3(4, 64, 1), 256, 0, stream>>>(oa);
}